// Round 4
// baseline (17457.178 us; speedup 1.0000x reference)
//
#include <hip/hip_runtime.h>
#include <math.h>

// Residual VQ matching a float32 numpy reference (R3-verified semantics):
//   scores = x2 + e2 - 2*(res @ emb.T) in f32, argmin = first-min.
//   e2/x2: numpy pairwise order (8 mod-8 accumulators, f32-rounded squares).
//   Hot path: fast fp32 scoring + top-2 margin; flagged rows do the full
//   replicated rescan (M = fl32(exact f64 dot)). Residual update plain f32.
// R4 perf: D-split (lane pair shares a row, 64 floats each, shfl_xor(32)
// combine) doubles TLP and halves rr registers; k-loop unroll 4 for ILP.

#define D_DIM 128
#define K_CB  1024
#define L_LVL 4

// force f32 rounding of a product (blocks fma contraction under -ffp-contract=fast)
static __device__ __forceinline__ float mulr(float a, float b) {
    float p = a * b;
    asm volatile("" : "+v"(p));
    return p;
}

static __device__ __forceinline__ float f4c(const float4& v, int c) {
    switch (c & 3) { case 0: return v.x; case 1: return v.y; case 2: return v.z; default: return v.w; }
}

__global__ __launch_bounds__(256, 3)
void rvq_kernel(const float* __restrict__ residual,
                const float* __restrict__ codebooks,
                float* __restrict__ out, int B) {
    __shared__ float e2s[L_LVL * K_CB];  // ||e||^2, numpy-pairwise f32 exact

    // e2 table (per block): numpy pairwise = 8 mod-8 accumulators + tree.
    // accA holds elems ==0..3 (mod 8), accB ==4..7 (mod 8); float4 loads.
    for (int i = threadIdx.x; i < L_LVL * K_CB; i += blockDim.x) {
        const float4* e = (const float4*)(codebooks + (size_t)i * D_DIM);
        float4 accA = make_float4(0.f, 0.f, 0.f, 0.f);
        float4 accB = make_float4(0.f, 0.f, 0.f, 0.f);
        #pragma unroll
        for (int m = 0; m < 32; m += 2) {
            float4 v = e[m];
            accA.x += mulr(v.x, v.x); accA.y += mulr(v.y, v.y);
            accA.z += mulr(v.z, v.z); accA.w += mulr(v.w, v.w);
            float4 w = e[m + 1];
            accB.x += mulr(w.x, w.x); accB.y += mulr(w.y, w.y);
            accB.z += mulr(w.z, w.z); accB.w += mulr(w.w, w.w);
        }
        e2s[i] = ((accA.x + accA.y) + (accA.z + accA.w)) +
                 ((accB.x + accB.y) + (accB.z + accB.w));
    }
    __syncthreads();

    const int lane   = threadIdx.x & 63;
    const int wave   = threadIdx.x >> 6;
    const int subrow = lane & 31;
    const int dh     = lane >> 5;           // which 64-float half of D
    const int row    = blockIdx.x * 128 + wave * 32 + subrow;
    if (row >= B) return;

    const float4* rp = (const float4*)(residual + (size_t)row * D_DIM + dh * 64);
    float4 rr[16];                          // own half of the residual
    #pragma unroll
    for (int j = 0; j < 16; ++j) rr[j] = rp[j];

    int   codes_i[L_LVL];
    float codes_f[L_LVL];

    for (int l = 0; l < L_LVL; ++l) {
        const float* cbl = codebooks + (size_t)l * K_CB * D_DIM;
        const float* e2l = &e2s[l * K_CB];

        float best = 3.4e38f, best2 = 3.4e38f;
        int bidx = 0;

        // ---- hot fp32 scoring: half-dot + cross-half shuffle ----
        #pragma unroll 4
        for (int k = 0; k < K_CB; ++k) {
            const float4* ek = (const float4*)(cbl + (size_t)k * D_DIM + dh * 64);
            float p0 = 0.f, p1 = 0.f, p2 = 0.f, p3 = 0.f;
            #pragma unroll
            for (int j = 0; j < 16; ++j) {
                float4 v = ek[j];
                p0 = fmaf(rr[j].x, v.x, p0);
                p1 = fmaf(rr[j].y, v.y, p1);
                p2 = fmaf(rr[j].z, v.z, p2);
                p3 = fmaf(rr[j].w, v.w, p3);
            }
            float p  = (p0 + p1) + (p2 + p3);
            float po = __shfl_xor(p, 32, 64);   // partner half's partial
            float sc = fmaf(-2.0f, p + po, e2l[k]);
            if (sc < best)       { best2 = best; best = sc; bidx = k; }
            else if (sc < best2) { best2 = sc; }
        }

        // ---- ambiguous: full replicated-f32 rescan (rare; both pair lanes
        //      execute identically -> same bidx) ----
        const float MARGIN = 4e-4f;
        if (best2 - best <= MARGIN) {
            // rebuild full residual bit-exactly: r0 minus chosen q's in order
            float4 rf[32];
            const float4* r0p = (const float4*)(residual + (size_t)row * D_DIM);
            #pragma unroll
            for (int j = 0; j < 32; ++j) rf[j] = r0p[j];
            for (int m = 0; m < l; ++m) {
                const float4* qm = (const float4*)(codebooks +
                    ((size_t)m * K_CB + codes_i[m]) * D_DIM);
                #pragma unroll
                for (int j = 0; j < 32; ++j) {
                    float4 v = qm[j];
                    rf[j].x -= v.x; rf[j].y -= v.y; rf[j].z -= v.z; rf[j].w -= v.w;
                }
            }
            // x2: numpy pairwise over fl32(r_i^2)
            float r8[8];
            #pragma unroll
            for (int j = 0; j < 8; ++j) {
                float v0 = f4c(rf[j >> 2], j);
                float acc = mulr(v0, v0);
                #pragma unroll
                for (int b = 1; b < 16; ++b) {
                    float v = f4c(rf[(j >> 2) + 2 * b], j);
                    acc += mulr(v, v);
                }
                r8[j] = acc;
            }
            float x2 = ((r8[0] + r8[1]) + (r8[2] + r8[3])) +
                       ((r8[4] + r8[5]) + (r8[6] + r8[7]));

            float bestS = 3.4e38f;
            int bi = 0;
            for (int k = 0; k < K_CB; ++k) {
                const float4* ek = (const float4*)(cbl + (size_t)k * D_DIM);
                double dd = 0.0;
                #pragma unroll
                for (int j = 0; j < 32; ++j) {
                    float4 v = ek[j];
                    dd = fma((double)v.x, (double)rf[j].x, dd);
                    dd = fma((double)v.y, (double)rf[j].y, dd);
                    dd = fma((double)v.z, (double)rf[j].z, dd);
                    dd = fma((double)v.w, (double)rf[j].w, dd);
                }
                float M = (float)dd;            // fl32(exact dot)
                float A = x2 + e2l[k];          // fl32(x2 + e2_k)
                float S = A - 2.0f * M;         // final rounding at |score|~128
                if (S < bestS) { bestS = S; bi = k; }
            }
            bidx = bi;
        }
        codes_i[l] = bidx;
        codes_f[l] = (float)bidx;

        // ---- residual update (own half): plain f32 r -= q ----
        const float4* q = (const float4*)(cbl + (size_t)bidx * D_DIM + dh * 64);
        #pragma unroll
        for (int j = 0; j < 16; ++j) {
            float4 v = q[j];
            rr[j].x -= v.x; rr[j].y -= v.y; rr[j].z -= v.z; rr[j].w -= v.w;
        }
    }

    // quantized (own half) = r0 - r_final
    float4* op = (float4*)(out + (size_t)row * D_DIM + dh * 64);
    #pragma unroll
    for (int j = 0; j < 16; ++j) {
        float4 r0 = rp[j];
        float4 o;
        o.x = r0.x - rr[j].x; o.y = r0.y - rr[j].y;
        o.z = r0.z - rr[j].z; o.w = r0.w - rr[j].w;
        op[j] = o;
    }

    if (dh == 0) {
        float4* cp = (float4*)(out + (size_t)B * D_DIM + (size_t)row * L_LVL);
        *cp = make_float4(codes_f[0], codes_f[1], codes_f[2], codes_f[3]);
    }
}

extern "C" void kernel_launch(void* const* d_in, const int* in_sizes, int n_in,
                              void* d_out, int out_size, void* d_ws, size_t ws_size,
                              hipStream_t stream) {
    const float* residual  = (const float*)d_in[0];
    const float* codebooks = (const float*)d_in[1];
    float* out = (float*)d_out;
    int B = in_sizes[0] / D_DIM;  // 131072
    // 2 threads per row (D halves) -> 128 rows per 256-thread block
    dim3 grid((B + 127) / 128), block(256);
    hipLaunchKernelGGL(rvq_kernel, grid, block, 0, stream,
                       residual, codebooks, out, B);
}

// Round 5
// 8914.892 us; speedup vs baseline: 1.9582x; 1.9582x over previous
//
#include <hip/hip_runtime.h>
#include <math.h>

// Residual VQ matching a float32 numpy reference (R3-verified semantics):
//   scores = x2 + e2 - 2*(res @ emb.T) in f32, argmin = first-min.
//   e2/x2: numpy pairwise order (8 mod-8 accumulators, f32-rounded squares).
//   Hot path: fast fp32 scoring + top-2 margin; flagged rows do the full
//   replicated rescan (M = fl32(exact f64 dot)). Residual update plain f32.
// R5 perf: stage 64-codeword chunks in LDS (coalesced copy, 2 barriers/chunk);
// hot loop reads codewords via wave-uniform ds_read_b128 broadcasts ->
// latency pipelined, FMA stream becomes critical path. 1 thread per row.

#define D_DIM 128
#define K_CB  1024
#define L_LVL 4
#define CHUNK 64
#define NCHUNK (K_CB / CHUNK)

// force f32 rounding of a product (blocks fma contraction under -ffp-contract=fast)
static __device__ __forceinline__ float mulr(float a, float b) {
    float p = a * b;
    asm volatile("" : "+v"(p));
    return p;
}

static __device__ __forceinline__ float f4c(const float4& v, int c) {
    switch (c & 3) { case 0: return v.x; case 1: return v.y; case 2: return v.z; default: return v.w; }
}

__global__ __launch_bounds__(256, 2)
void rvq_kernel(const float* __restrict__ residual,
                const float* __restrict__ codebooks,
                float* __restrict__ out, int B) {
    __shared__ float e2s[L_LVL * K_CB];    // 16 KB: ||e||^2, numpy-pairwise f32
    __shared__ float cw[CHUNK * D_DIM];    // 32 KB: staged codeword chunk

    // e2 table (per block): numpy pairwise = 8 mod-8 accumulators + tree.
    for (int i = threadIdx.x; i < L_LVL * K_CB; i += blockDim.x) {
        const float4* e = (const float4*)(codebooks + (size_t)i * D_DIM);
        float4 accA = make_float4(0.f, 0.f, 0.f, 0.f);
        float4 accB = make_float4(0.f, 0.f, 0.f, 0.f);
        #pragma unroll
        for (int m = 0; m < 32; m += 2) {
            float4 v = e[m];
            accA.x += mulr(v.x, v.x); accA.y += mulr(v.y, v.y);
            accA.z += mulr(v.z, v.z); accA.w += mulr(v.w, v.w);
            float4 w = e[m + 1];
            accB.x += mulr(w.x, w.x); accB.y += mulr(w.y, w.y);
            accB.z += mulr(w.z, w.z); accB.w += mulr(w.w, w.w);
        }
        e2s[i] = ((accA.x + accA.y) + (accA.z + accA.w)) +
                 ((accB.x + accB.y) + (accB.z + accB.w));
    }
    __syncthreads();

    const int row = blockIdx.x * blockDim.x + threadIdx.x;  // B % 256 == 0

    const float4* rp = (const float4*)(residual + (size_t)row * D_DIM);
    float4 rr[32];
    #pragma unroll
    for (int j = 0; j < 32; ++j) rr[j] = rp[j];

    int   codes_i[L_LVL];
    float codes_f[L_LVL];

    for (int l = 0; l < L_LVL; ++l) {
        const float* cbl = codebooks + (size_t)l * K_CB * D_DIM;
        const float* e2l = &e2s[l * K_CB];

        float best = 3.4e38f, best2 = 3.4e38f;
        int bidx = 0;

        for (int c = 0; c < NCHUNK; ++c) {
            __syncthreads();  // previous chunk fully consumed
            // ---- stage chunk c into LDS (coalesced float4) ----
            {
                const float4* src4 = (const float4*)(cbl + (size_t)c * CHUNK * D_DIM);
                float4* dst4 = (float4*)cw;
                #pragma unroll
                for (int it = 0; it < (CHUNK * D_DIM / 4) / 256; ++it) {
                    int idx = it * 256 + threadIdx.x;
                    dst4[idx] = src4[idx];
                }
            }
            __syncthreads();

            // ---- hot fp32 scoring over staged chunk ----
            const float4* cwv = (const float4*)cw;
            for (int kk = 0; kk < CHUNK; ++kk) {
                const float4* ek = &cwv[kk * 32];   // wave-uniform -> broadcast
                float p0 = 0.f, p1 = 0.f, p2 = 0.f, p3 = 0.f;
                #pragma unroll
                for (int j = 0; j < 32; ++j) {
                    float4 v = ek[j];
                    p0 = fmaf(rr[j].x, v.x, p0);
                    p1 = fmaf(rr[j].y, v.y, p1);
                    p2 = fmaf(rr[j].z, v.z, p2);
                    p3 = fmaf(rr[j].w, v.w, p3);
                }
                int k = c * CHUNK + kk;
                float sc = fmaf(-2.0f, (p0 + p1) + (p2 + p3), e2l[k]);
                if (sc < best)       { best2 = best; best = sc; bidx = k; }
                else if (sc < best2) { best2 = sc; }
            }
        }

        // ---- ambiguous: full replicated-f32 rescan (rare, reads global) ----
        const float MARGIN = 4e-4f;
        if (best2 - best <= MARGIN) {
            // x2: numpy pairwise over fl32(r_i^2); elem i=j+8b -> rr[(j>>2)+2b]
            float r8[8];
            #pragma unroll
            for (int j = 0; j < 8; ++j) {
                float v0 = f4c(rr[j >> 2], j);
                float acc = mulr(v0, v0);
                #pragma unroll
                for (int b = 1; b < 16; ++b) {
                    float v = f4c(rr[(j >> 2) + 2 * b], j);
                    acc += mulr(v, v);
                }
                r8[j] = acc;
            }
            float x2 = ((r8[0] + r8[1]) + (r8[2] + r8[3])) +
                       ((r8[4] + r8[5]) + (r8[6] + r8[7]));

            float bestS = 3.4e38f;
            int bi = 0;
            for (int k = 0; k < K_CB; ++k) {
                const float4* ek = (const float4*)(cbl + (size_t)k * D_DIM);
                double dd = 0.0;
                #pragma unroll
                for (int j = 0; j < 32; ++j) {
                    float4 v = ek[j];
                    dd = fma((double)v.x, (double)rr[j].x, dd);
                    dd = fma((double)v.y, (double)rr[j].y, dd);
                    dd = fma((double)v.z, (double)rr[j].z, dd);
                    dd = fma((double)v.w, (double)rr[j].w, dd);
                }
                float M = (float)dd;            // fl32(exact dot)
                float A = x2 + e2l[k];          // fl32(x2 + e2_k)
                float S = A - 2.0f * M;         // final rounding at |score|~128
                if (S < bestS) { bestS = S; bi = k; }  // strict <: first-min
            }
            bidx = bi;
        }
        codes_i[l] = bidx;
        codes_f[l] = (float)bidx;

        // ---- residual update: plain f32 r -= q (per-thread gather, L2-hit) ----
        const float4* q = (const float4*)(cbl + (size_t)bidx * D_DIM);
        #pragma unroll
        for (int j = 0; j < 32; ++j) {
            float4 v = q[j];
            rr[j].x -= v.x; rr[j].y -= v.y; rr[j].z -= v.z; rr[j].w -= v.w;
        }
    }

    // quantized = r0 - r_final
    float4* op = (float4*)(out + (size_t)row * D_DIM);
    #pragma unroll
    for (int j = 0; j < 32; ++j) {
        float4 r0 = rp[j];
        float4 o;
        o.x = r0.x - rr[j].x; o.y = r0.y - rr[j].y;
        o.z = r0.z - rr[j].z; o.w = r0.w - rr[j].w;
        op[j] = o;
    }

    float4* cp = (float4*)(out + (size_t)B * D_DIM + (size_t)row * L_LVL);
    *cp = make_float4(codes_f[0], codes_f[1], codes_f[2], codes_f[3]);
}

extern "C" void kernel_launch(void* const* d_in, const int* in_sizes, int n_in,
                              void* d_out, int out_size, void* d_ws, size_t ws_size,
                              hipStream_t stream) {
    const float* residual  = (const float*)d_in[0];
    const float* codebooks = (const float*)d_in[1];
    float* out = (float*)d_out;
    int B = in_sizes[0] / D_DIM;  // 131072
    dim3 grid(B / 256), block(256);
    hipLaunchKernelGGL(rvq_kernel, grid, block, 0, stream,
                       residual, codebooks, out, B);
}

// Round 6
// 3033.230 us; speedup vs baseline: 5.7553x; 2.9391x over previous
//
#include <hip/hip_runtime.h>
#include <math.h>

// Residual VQ matching a float32 numpy reference (R3-verified semantics):
//   scores = x2 + e2 - 2*(res @ emb.T) in f32, argmin = first-min.
// R6 structure:
//   rvq_e2:    pairwise-exact ||e||^2 table -> d_ws (R3-verified order)
//   rvq_main:  GEMM-tiled hot path. 128 rows/block in LDS, 128-k tiles in
//              LDS, 8x8 register tiles/thread, shfl-merged top-2 + margin.
//              Ambiguous rows appended to a fixup list in d_ws.
//   rvq_fixup: one block per flagged row; replicated-f32 reference scoring
//              (pairwise x2/e2, M=fl32(f64 dot), S=(x2+e2)-2M, first-min),
//              overwrites quantized+codes for that row.

#define D_DIM  128
#define K_CB   1024
#define L_LVL  4
#define BROWS  128
#define KTILE  128
#define LSTR   132   // padded LDS row stride in floats (16B-aligned)
#define MARGIN 4e-4f

// force f32 rounding of a product (blocks fma contraction)
static __device__ __forceinline__ float mulr(float a, float b) {
    float p = a * b;
    asm volatile("" : "+v"(p));
    return p;
}

// ---------------- e2 table (pairwise, replicated numpy order) ----------------
__global__ void rvq_e2(const float* __restrict__ codebooks, float* __restrict__ e2p) {
    int i = blockIdx.x * blockDim.x + threadIdx.x;
    if (i >= L_LVL * K_CB) return;
    const float* e = codebooks + (size_t)i * D_DIM;
    float r8[8];
    #pragma unroll
    for (int j = 0; j < 8; ++j) r8[j] = mulr(e[j], e[j]);
    #pragma unroll
    for (int b = 1; b < 16; ++b)
        #pragma unroll
        for (int j = 0; j < 8; ++j) r8[j] += mulr(e[b * 8 + j], e[b * 8 + j]);
    e2p[i] = ((r8[0] + r8[1]) + (r8[2] + r8[3])) + ((r8[4] + r8[5]) + (r8[6] + r8[7]));
}

// ---------------- hot kernel ----------------
__global__ __launch_bounds__(256, 1)
void rvq_main(const float* __restrict__ residual,
              const float* __restrict__ codebooks,
              const float* __restrict__ e2p,
              unsigned* __restrict__ flagcnt, unsigned* __restrict__ flaglist,
              unsigned flagcap, float* __restrict__ out, int B) {
    __shared__ float rrs[BROWS * LSTR];     // 67584 B residuals
    __shared__ float cws[KTILE * LSTR];     // 67584 B codeword tile
    __shared__ int   bidxs[L_LVL][BROWS];   // 2048 B

    const int tid = threadIdx.x;
    const int rg  = tid >> 4;    // 0..15 row group
    const int kg  = tid & 15;    // 0..15 k group
    const int row0 = blockIdx.x * BROWS;

    // stage residuals: thread -> row=tid>>1, half=tid&1 (coalesced)
    {
        int r = tid >> 1, h = tid & 1;
        const float4* src = (const float4*)(residual + (size_t)(row0 + r) * D_DIM + h * 64);
        #pragma unroll
        for (int c = 0; c < 16; ++c)
            *(float4*)&rrs[r * LSTR + h * 64 + c * 4] = src[c];
    }
    __syncthreads();

    int flagmask = 0;

    for (int l = 0; l < L_LVL; ++l) {
        const float* cbl = codebooks + (size_t)l * K_CB * D_DIM;

        float rbest[8], rbest2[8];
        int   ridx[8];
        #pragma unroll
        for (int i = 0; i < 8; ++i) { rbest[i] = 3.4e38f; rbest2[i] = 3.4e38f; ridx[i] = 0; }

        for (int t = 0; t < K_CB / KTILE; ++t) {
            __syncthreads();   // previous cws fully consumed
            // stage k-tile (coalesced 16B)
            {
                const float4* src = (const float4*)(cbl + (size_t)t * KTILE * D_DIM);
                #pragma unroll
                for (int it = 0; it < 16; ++it) {
                    int f = it * 256 + tid;
                    int k = f >> 5, c = f & 31;
                    *(float4*)&cws[k * LSTR + c * 4] = src[f];
                }
            }
            __syncthreads();

            float acc[8][8];
            #pragma unroll
            for (int i = 0; i < 8; ++i)
                #pragma unroll
                for (int j = 0; j < 8; ++j) acc[i][j] = 0.f;

            #pragma unroll 2
            for (int d = 0; d < 32; ++d) {
                float4 rv[8], kv[8];
                #pragma unroll
                for (int i = 0; i < 8; ++i)
                    rv[i] = *(const float4*)&rrs[(rg + 16 * i) * LSTR + d * 4];
                #pragma unroll
                for (int j = 0; j < 8; ++j)
                    kv[j] = *(const float4*)&cws[(kg + 16 * j) * LSTR + d * 4];
                #pragma unroll
                for (int i = 0; i < 8; ++i)
                    #pragma unroll
                    for (int j = 0; j < 8; ++j) {
                        float a = acc[i][j];
                        a = fmaf(rv[i].x, kv[j].x, a);
                        a = fmaf(rv[i].y, kv[j].y, a);
                        a = fmaf(rv[i].z, kv[j].z, a);
                        a = fmaf(rv[i].w, kv[j].w, a);
                        acc[i][j] = a;
                    }
            }

            // scores + running top-2 (k ascending within thread)
            #pragma unroll
            for (int j = 0; j < 8; ++j) {
                int k = t * KTILE + kg + 16 * j;
                float e2 = e2p[l * K_CB + k];
                #pragma unroll
                for (int i = 0; i < 8; ++i) {
                    float sc = fmaf(-2.0f, acc[i][j], e2);
                    if (sc < rbest[i])       { rbest2[i] = rbest[i]; rbest[i] = sc; ridx[i] = k; }
                    else if (sc < rbest2[i]) { rbest2[i] = sc; }
                }
            }
        }

        // merge top-2 across the 16 k-threads (consecutive lanes; first-min)
        #pragma unroll
        for (int i = 0; i < 8; ++i) {
            float b = rbest[i], b2 = rbest2[i];
            int   ix = ridx[i];
            #pragma unroll
            for (int m = 1; m < 16; m <<= 1) {
                float bo  = __shfl_xor(b, m, 64);
                float b2o = __shfl_xor(b2, m, 64);
                int   io  = __shfl_xor(ix, m, 64);
                float nb2 = fminf(fmaxf(b, bo), fminf(b2, b2o));
                if (bo < b || (bo == b && io < ix)) { b = bo; ix = io; }
                b2 = nb2;
            }
            rbest[i] = b; rbest2[i] = b2; ridx[i] = ix;
            if (b2 - b <= MARGIN) flagmask |= (1 << i);
        }
        if (kg == 0) {
            #pragma unroll
            for (int i = 0; i < 8; ++i) bidxs[l][rg + 16 * i] = ridx[i];
        }
        __syncthreads();

        // residual update: row = tid>>1, half = tid&1
        {
            int r = tid >> 1, h = tid & 1;
            int bi = bidxs[l][r];
            const float4* q = (const float4*)(cbl + (size_t)bi * D_DIM + h * 64);
            #pragma unroll
            for (int c = 0; c < 16; ++c) {
                float4 v = q[c];
                float4* p = (float4*)&rrs[r * LSTR + h * 64 + c * 4];
                float4 x = *p;
                x.x -= v.x; x.y -= v.y; x.z -= v.z; x.w -= v.w;
                *p = x;
            }
        }
        __syncthreads();
    }

    // append flagged rows (kg==0 holds identical merged data)
    if (kg == 0 && flagmask) {
        #pragma unroll
        for (int i = 0; i < 8; ++i)
            if (flagmask & (1 << i)) {
                unsigned pos = atomicAdd(flagcnt, 1u);
                if (pos < flagcap) flaglist[pos] = row0 + rg + 16 * i;
            }
    }

    // quantized = r0 - r_final
    {
        int r = tid >> 1, h = tid & 1;
        const float4* r0 = (const float4*)(residual + (size_t)(row0 + r) * D_DIM + h * 64);
        float4* op = (float4*)(out + (size_t)(row0 + r) * D_DIM + h * 64);
        #pragma unroll
        for (int c = 0; c < 16; ++c) {
            float4 a = r0[c];
            float4 b = *(const float4*)&rrs[r * LSTR + h * 64 + c * 4];
            op[c] = make_float4(a.x - b.x, a.y - b.y, a.z - b.z, a.w - b.w);
        }
    }
    if (tid < BROWS) {
        float4* cp = (float4*)(out + (size_t)B * D_DIM + (size_t)(row0 + tid) * L_LVL);
        *cp = make_float4((float)bidxs[0][tid], (float)bidxs[1][tid],
                          (float)bidxs[2][tid], (float)bidxs[3][tid]);
    }
}

// ---------------- fixup: replicated reference semantics per flagged row ----------------
__global__ __launch_bounds__(256, 1)
void rvq_fixup(const float* __restrict__ residual,
               const float* __restrict__ codebooks,
               const float* __restrict__ e2p,
               const unsigned* __restrict__ flagcnt,
               const unsigned* __restrict__ flaglist,
               unsigned flagcap, float* __restrict__ out, int B) {
    __shared__ float rbuf[D_DIM];
    __shared__ float r0buf[D_DIM];
    __shared__ float x2s;
    __shared__ float redS[256];
    __shared__ int   redK[256];
    __shared__ int   codes_s[L_LVL];

    unsigned n = *flagcnt;
    if (n > flagcap) n = flagcap;

    for (unsigned b = blockIdx.x; b < n; b += gridDim.x) {
        int row = (int)flaglist[b];
        if (threadIdx.x < 32) {
            float4 v = ((const float4*)(residual + (size_t)row * D_DIM))[threadIdx.x];
            *(float4*)&rbuf[threadIdx.x * 4]  = v;
            *(float4*)&r0buf[threadIdx.x * 4] = v;
        }
        __syncthreads();

        for (int l = 0; l < L_LVL; ++l) {
            const float* cbl = codebooks + (size_t)l * K_CB * D_DIM;
            if (threadIdx.x == 0) {
                float r8[8];
                #pragma unroll
                for (int j = 0; j < 8; ++j) r8[j] = mulr(rbuf[j], rbuf[j]);
                for (int bb = 1; bb < 16; ++bb)
                    #pragma unroll
                    for (int j = 0; j < 8; ++j) r8[j] += mulr(rbuf[bb * 8 + j], rbuf[bb * 8 + j]);
                x2s = ((r8[0] + r8[1]) + (r8[2] + r8[3])) + ((r8[4] + r8[5]) + (r8[6] + r8[7]));
            }
            __syncthreads();
            float x2 = x2s;

            float bS = 3.4e38f;
            int   bK = 0x7fffffff;
            for (int m = 0; m < 4; ++m) {
                int k = threadIdx.x + m * 256;
                const float4* ek = (const float4*)(cbl + (size_t)k * D_DIM);
                double dd = 0.0;
                for (int c = 0; c < 32; ++c) {
                    float4 v = ek[c];
                    dd = fma((double)v.x, (double)rbuf[c * 4 + 0], dd);
                    dd = fma((double)v.y, (double)rbuf[c * 4 + 1], dd);
                    dd = fma((double)v.z, (double)rbuf[c * 4 + 2], dd);
                    dd = fma((double)v.w, (double)rbuf[c * 4 + 3], dd);
                }
                float M = (float)dd;                 // fl32(exact dot)
                float A = x2 + e2p[l * K_CB + k];    // fl32(x2 + e2)
                float S = A - 2.0f * M;              // final f32 rounding
                if (S < bS || (S == bS && k < bK)) { bS = S; bK = k; }
            }
            redS[threadIdx.x] = bS; redK[threadIdx.x] = bK;
            __syncthreads();
            for (int s = 128; s > 0; s >>= 1) {
                if (threadIdx.x < (unsigned)s) {
                    float So = redS[threadIdx.x + s];
                    int   Ko = redK[threadIdx.x + s];
                    if (So < redS[threadIdx.x] ||
                        (So == redS[threadIdx.x] && Ko < redK[threadIdx.x])) {
                        redS[threadIdx.x] = So; redK[threadIdx.x] = Ko;
                    }
                }
                __syncthreads();
            }
            int bi = redK[0];
            if (threadIdx.x == 0) codes_s[l] = bi;
            if (threadIdx.x < 32) {
                float4 q = ((const float4*)(cbl + (size_t)bi * D_DIM))[threadIdx.x];
                float4* p = (float4*)&rbuf[threadIdx.x * 4];
                float4 x = *p;
                x.x -= q.x; x.y -= q.y; x.z -= q.z; x.w -= q.w;
                *p = x;
            }
            __syncthreads();
        }

        if (threadIdx.x < 32) {
            float4 a = *(float4*)&r0buf[threadIdx.x * 4];
            float4 r = *(float4*)&rbuf[threadIdx.x * 4];
            ((float4*)(out + (size_t)row * D_DIM))[threadIdx.x] =
                make_float4(a.x - r.x, a.y - r.y, a.z - r.z, a.w - r.w);
        }
        if (threadIdx.x == 0) {
            float4* cp = (float4*)(out + (size_t)B * D_DIM + (size_t)row * L_LVL);
            *cp = make_float4((float)codes_s[0], (float)codes_s[1],
                              (float)codes_s[2], (float)codes_s[3]);
        }
        __syncthreads();
    }
}

extern "C" void kernel_launch(void* const* d_in, const int* in_sizes, int n_in,
                              void* d_out, int out_size, void* d_ws, size_t ws_size,
                              hipStream_t stream) {
    const float* residual  = (const float*)d_in[0];
    const float* codebooks = (const float*)d_in[1];
    float* out = (float*)d_out;
    int B = in_sizes[0] / D_DIM;  // 131072

    float*    e2p      = (float*)d_ws;                         // 16 KB
    unsigned* flagcnt  = (unsigned*)((char*)d_ws + 16384);
    unsigned* flaglist = flagcnt + 4;
    unsigned  flagcap  = 0;
    if (ws_size > 16384 + 64)
        flagcap = (unsigned)((ws_size - 16384 - 64) / sizeof(unsigned));
    if (flagcap > (unsigned)B) flagcap = (unsigned)B;

    hipMemsetAsync(flagcnt, 0, sizeof(unsigned), stream);
    hipLaunchKernelGGL(rvq_e2, dim3(16), dim3(256), 0, stream, codebooks, e2p);
    hipLaunchKernelGGL(rvq_main, dim3(B / BROWS), dim3(256), 0, stream,
                       residual, codebooks, e2p, flagcnt, flaglist, flagcap, out, B);
    hipLaunchKernelGGL(rvq_fixup, dim3(512), dim3(256), 0, stream,
                       residual, codebooks, e2p, flagcnt, flaglist, flagcap, out, B);
}

// Round 7
// 935.371 us; speedup vs baseline: 18.6634x; 3.2428x over previous
//
#include <hip/hip_runtime.h>
#include <math.h>

// Residual VQ matching a float32 numpy reference (R3/R6-verified semantics):
//   scores = x2 + e2 - 2*(res @ emb.T) in f32, argmin = first-min.
// R7: bf16x3 MFMA hot path (mfma_f32_32x32x16_bf16, dot = rh*eh+rh*el+rl*eh,
// worst-case score err < 5e-4 < MARGIN/2), margin-flagged rows replayed by
// the verified exact fixup kernel. Codebook pre-split to bf16 hi/lo in d_ws.
// Falls back to the verified R6 all-f32 path if d_ws is too small.

#define D_DIM 128
#define K_CB  1024
#define L_LVL 4
#define LK    (L_LVL * K_CB)
#define LKD   (LK * D_DIM)
#define MARGIN_MFMA 1e-3f
#define MARGIN_F32  4e-4f

typedef __bf16 bf16x8 __attribute__((ext_vector_type(8)));
typedef float  f32x16 __attribute__((ext_vector_type(16)));

// force f32 rounding of a product (blocks fma contraction)
static __device__ __forceinline__ float mulr(float a, float b) {
    float p = a * b;
    asm volatile("" : "+v"(p));
    return p;
}

static __device__ __forceinline__ float f4c(const float4& v, int c) {
    switch (c & 3) { case 0: return v.x; case 1: return v.y; case 2: return v.z; default: return v.w; }
}

// ---------------- e2 table (pairwise, replicated numpy order) ----------------
__global__ void rvq_e2(const float* __restrict__ codebooks, float* __restrict__ e2p) {
    int i = blockIdx.x * blockDim.x + threadIdx.x;
    if (i >= LK) return;
    const float* e = codebooks + (size_t)i * D_DIM;
    float r8[8];
    #pragma unroll
    for (int j = 0; j < 8; ++j) r8[j] = mulr(e[j], e[j]);
    #pragma unroll
    for (int b = 1; b < 16; ++b)
        #pragma unroll
        for (int j = 0; j < 8; ++j) r8[j] += mulr(e[b * 8 + j], e[b * 8 + j]);
    e2p[i] = ((r8[0] + r8[1]) + (r8[2] + r8[3])) + ((r8[4] + r8[5]) + (r8[6] + r8[7]));
}

// ---------------- codebook bf16 hi/lo split ----------------
__global__ void rvq_split(const float* __restrict__ cb,
                          __bf16* __restrict__ hi, __bf16* __restrict__ lo) {
    int i = blockIdx.x * blockDim.x + threadIdx.x;   // over LKD/4
    float4 v = ((const float4*)cb)[i];
    float f[4] = {v.x, v.y, v.z, v.w};
    #pragma unroll
    for (int e = 0; e < 4; ++e) {
        __bf16 h = (__bf16)f[e];
        hi[i * 4 + e] = h;
        lo[i * 4 + e] = (__bf16)(f[e] - (float)h);
    }
}

// ---------------- stage one 32-codeword tile (hi+lo) into LDS ----------------
static __device__ __forceinline__ void stage_tile(
    const __bf16* cbhL, const __bf16* cblL, int t,
    __bf16* dsth, __bf16* dstl, int wave, int lane) {
    const int k0 = t * 32;
    const size_t off = (size_t)(k0 + (lane & 31)) * D_DIM + (lane >> 5) * 8;
    #pragma unroll
    for (int c = 0; c < 2; ++c) {
        const int it = wave * 2 + c;
        __builtin_amdgcn_global_load_lds(
            (const __attribute__((address_space(1))) void*)(cbhL + off + it * 16),
            (__attribute__((address_space(3))) void*)(dsth + it * 512), 16, 0, 0);
        __builtin_amdgcn_global_load_lds(
            (const __attribute__((address_space(1))) void*)(cblL + off + it * 16),
            (__attribute__((address_space(3))) void*)(dstl + it * 512), 16, 0, 0);
    }
}

// ---------------- MFMA hot kernel ----------------
__global__ __launch_bounds__(256, 2)
void rvq_mfma(const float* __restrict__ residual,
              const float* __restrict__ codebooks,
              const __bf16* __restrict__ cbh, const __bf16* __restrict__ cbl,
              const float* __restrict__ e2p,
              unsigned* __restrict__ flagcnt, unsigned* __restrict__ flaglist,
              unsigned flagcap, float* __restrict__ out, int B) {
    __shared__ __align__(16) __bf16 bufh[2][32 * D_DIM];   // 2 x 8 KB
    __shared__ __align__(16) __bf16 bufl[2][32 * D_DIM];   // 2 x 8 KB
    __shared__ float e2s[LK];                              // 16 KB
    __shared__ int   bidxs[L_LVL][128];
    __shared__ unsigned char flg[128];

    const int tid  = threadIdx.x;
    const int wave = tid >> 6;
    const int lane = tid & 63;
    const int col  = lane & 31;
    const int h    = lane >> 5;
    const int rb   = wave * 32;
    const int grow = blockIdx.x * 128 + rb + col;   // this lane's A-row

    {   // e2 table -> LDS (coalesced)
        const float4* s = (const float4*)e2p;
        float4* d = (float4*)e2s;
        #pragma unroll
        for (int i = 0; i < 4; ++i) d[i * 256 + tid] = s[i * 256 + tid];
    }
    if (tid < 128) flg[tid] = 0;

    // A fragments: residual row split to bf16 hi/lo, kept in registers.
    // lane covers row=rb+col, D-elems kk*16 + h*8 + e  (same k-formula as B).
    bf16x8 Ah[8], Al[8];
    {
        const float* rowp = residual + (size_t)grow * D_DIM;
        #pragma unroll
        for (int kk = 0; kk < 8; ++kk) {
            const int d0 = kk * 16 + h * 8;
            float4 a = *(const float4*)(rowp + d0);
            float4 b = *(const float4*)(rowp + d0 + 4);
            float f[8] = {a.x, a.y, a.z, a.w, b.x, b.y, b.z, b.w};
            #pragma unroll
            for (int e = 0; e < 8; ++e) {
                __bf16 hh = (__bf16)f[e];
                Ah[kk][e] = hh;
                Al[kk][e] = (__bf16)(f[e] - (float)hh);
            }
        }
    }

    for (int l = 0; l < L_LVL; ++l) {
        const __bf16* cbhL = cbh + (size_t)l * K_CB * D_DIM;
        const __bf16* cblL = cbl + (size_t)l * K_CB * D_DIM;

        float rbest[16], rbest2[16]; int ridx[16];
        #pragma unroll
        for (int s = 0; s < 16; ++s) { rbest[s] = 3.4e38f; rbest2[s] = 3.4e38f; ridx[s] = 0x7fffffff; }

        stage_tile(cbhL, cblL, 0, &bufh[0][0], &bufl[0][0], wave, lane);
        __syncthreads();

        for (int t = 0; t < 32; ++t) {
            const int cur = t & 1;
            if (t < 31)
                stage_tile(cbhL, cblL, t + 1, &bufh[cur ^ 1][0], &bufl[cur ^ 1][0], wave, lane);

            f32x16 accA, accB;
            #pragma unroll
            for (int s = 0; s < 16; ++s) { accA[s] = 0.f; accB[s] = 0.f; }

            const __bf16* bh = &bufh[cur][0];
            const __bf16* bl = &bufl[cur][0];
            #pragma unroll
            for (int kk = 0; kk < 8; ++kk) {
                bf16x8 Bh = *(const bf16x8*)(bh + kk * 512 + lane * 8);
                bf16x8 Bl = *(const bf16x8*)(bl + kk * 512 + lane * 8);
                if (kk & 1) {
                    accB = __builtin_amdgcn_mfma_f32_32x32x16_bf16(Ah[kk], Bh, accB, 0, 0, 0);
                    accB = __builtin_amdgcn_mfma_f32_32x32x16_bf16(Ah[kk], Bl, accB, 0, 0, 0);
                    accB = __builtin_amdgcn_mfma_f32_32x32x16_bf16(Al[kk], Bh, accB, 0, 0, 0);
                } else {
                    accA = __builtin_amdgcn_mfma_f32_32x32x16_bf16(Ah[kk], Bh, accA, 0, 0, 0);
                    accA = __builtin_amdgcn_mfma_f32_32x32x16_bf16(Ah[kk], Bl, accA, 0, 0, 0);
                    accA = __builtin_amdgcn_mfma_f32_32x32x16_bf16(Al[kk], Bh, accA, 0, 0, 0);
                }
            }

            const float e2k = e2s[l * K_CB + t * 32 + col];
            const int k = t * 32 + col;
            #pragma unroll
            for (int s = 0; s < 16; ++s) {
                float sc = fmaf(-2.f, accA[s] + accB[s], e2k);
                if (sc < rbest[s])       { rbest2[s] = rbest[s]; rbest[s] = sc; ridx[s] = k; }
                else if (sc < rbest2[s]) { rbest2[s] = sc; }
            }
            __syncthreads();   // tile consumed; next-tile stage loads drained
        }

        // merge top-2 across the 32 cols (within each 32-lane half)
        #pragma unroll
        for (int s = 0; s < 16; ++s) {
            float b = rbest[s], b2 = rbest2[s]; int ix = ridx[s];
            #pragma unroll
            for (int m = 1; m <= 16; m <<= 1) {
                float bo  = __shfl_xor(b,  m, 64);
                float b2o = __shfl_xor(b2, m, 64);
                int   io  = __shfl_xor(ix, m, 64);
                float nb2 = fminf(fmaxf(b, bo), fminf(b2, b2o));
                if (bo < b || (bo == b && io < ix)) { b = bo; ix = io; }
                b2 = nb2;
            }
            const int rloc = (s & 3) + 8 * (s >> 2) + 4 * h;   // verified C row map
            if (col == 0) {
                bidxs[l][rb + rloc] = ix;
                if (b2 - b <= MARGIN_MFMA) flg[rb + rloc] = 1;
            }
        }
        __syncthreads();

        // residual update in f32, re-split to bf16 pair (drift < margin budget)
        {
            const int bi = bidxs[l][rb + col];
            const float* qp = codebooks + ((size_t)l * K_CB + bi) * D_DIM;
            #pragma unroll
            for (int kk = 0; kk < 8; ++kk) {
                const int d0 = kk * 16 + h * 8;
                float4 qa = *(const float4*)(qp + d0);
                float4 qb = *(const float4*)(qp + d0 + 4);
                float q[8] = {qa.x, qa.y, qa.z, qa.w, qb.x, qb.y, qb.z, qb.w};
                #pragma unroll
                for (int e = 0; e < 8; ++e) {
                    float r = ((float)Ah[kk][e] + (float)Al[kk][e]) - q[e];
                    __bf16 hh = (__bf16)r;
                    Ah[kk][e] = hh;
                    Al[kk][e] = (__bf16)(r - (float)hh);
                }
            }
        }
    }

    // quantized = r0 - r_final  (bf16-pair error ~1e-5 << threshold 20.48)
    {
        const float* rowp = residual + (size_t)grow * D_DIM;
        float* op = out + (size_t)grow * D_DIM;
        #pragma unroll
        for (int kk = 0; kk < 8; ++kk) {
            const int d0 = kk * 16 + h * 8;
            float4 a = *(const float4*)(rowp + d0);
            float4 b = *(const float4*)(rowp + d0 + 4);
            float f[8] = {a.x, a.y, a.z, a.w, b.x, b.y, b.z, b.w};
            float o[8];
            #pragma unroll
            for (int e = 0; e < 8; ++e)
                o[e] = f[e] - ((float)Ah[kk][e] + (float)Al[kk][e]);
            *(float4*)(op + d0)     = make_float4(o[0], o[1], o[2], o[3]);
            *(float4*)(op + d0 + 4) = make_float4(o[4], o[5], o[6], o[7]);
        }
    }
    if (tid < 128) {
        int row = blockIdx.x * 128 + tid;
        float4* cp = (float4*)(out + (size_t)B * D_DIM + (size_t)row * L_LVL);
        *cp = make_float4((float)bidxs[0][tid], (float)bidxs[1][tid],
                          (float)bidxs[2][tid], (float)bidxs[3][tid]);
        if (flg[tid]) {
            unsigned pos = atomicAdd(flagcnt, 1u);
            if (pos < flagcap) flaglist[pos] = row;
        }
    }
}

// ---------------- R6 fallback hot kernel (verified, all-f32) ----------------
#define BROWS  128
#define KTILE  128
#define LSTR   132

__global__ __launch_bounds__(256, 1)
void rvq_main(const float* __restrict__ residual,
              const float* __restrict__ codebooks,
              const float* __restrict__ e2p,
              unsigned* __restrict__ flagcnt, unsigned* __restrict__ flaglist,
              unsigned flagcap, float* __restrict__ out, int B) {
    __shared__ float rrs[BROWS * LSTR];
    __shared__ float cws[KTILE * LSTR];
    __shared__ int   bidxs[L_LVL][BROWS];

    const int tid = threadIdx.x;
    const int rg  = tid >> 4;
    const int kg  = tid & 15;
    const int row0 = blockIdx.x * BROWS;

    {
        int r = tid >> 1, hh = tid & 1;
        const float4* src = (const float4*)(residual + (size_t)(row0 + r) * D_DIM + hh * 64);
        #pragma unroll
        for (int c = 0; c < 16; ++c)
            *(float4*)&rrs[r * LSTR + hh * 64 + c * 4] = src[c];
    }
    __syncthreads();

    int flagmask = 0;

    for (int l = 0; l < L_LVL; ++l) {
        const float* cbl = codebooks + (size_t)l * K_CB * D_DIM;

        float rbest[8], rbest2[8];
        int   ridx[8];
        #pragma unroll
        for (int i = 0; i < 8; ++i) { rbest[i] = 3.4e38f; rbest2[i] = 3.4e38f; ridx[i] = 0; }

        for (int t = 0; t < K_CB / KTILE; ++t) {
            __syncthreads();
            {
                const float4* src = (const float4*)(cbl + (size_t)t * KTILE * D_DIM);
                #pragma unroll
                for (int it = 0; it < 16; ++it) {
                    int f = it * 256 + tid;
                    int k = f >> 5, c = f & 31;
                    *(float4*)&cws[k * LSTR + c * 4] = src[f];
                }
            }
            __syncthreads();

            float acc[8][8];
            #pragma unroll
            for (int i = 0; i < 8; ++i)
                #pragma unroll
                for (int j = 0; j < 8; ++j) acc[i][j] = 0.f;

            #pragma unroll 2
            for (int d = 0; d < 32; ++d) {
                float4 rv[8], kv[8];
                #pragma unroll
                for (int i = 0; i < 8; ++i)
                    rv[i] = *(const float4*)&rrs[(rg + 16 * i) * LSTR + d * 4];
                #pragma unroll
                for (int j = 0; j < 8; ++j)
                    kv[j] = *(const float4*)&cws[(kg + 16 * j) * LSTR + d * 4];
                #pragma unroll
                for (int i = 0; i < 8; ++i)
                    #pragma unroll
                    for (int j = 0; j < 8; ++j) {
                        float a = acc[i][j];
                        a = fmaf(rv[i].x, kv[j].x, a);
                        a = fmaf(rv[i].y, kv[j].y, a);
                        a = fmaf(rv[i].z, kv[j].z, a);
                        a = fmaf(rv[i].w, kv[j].w, a);
                        acc[i][j] = a;
                    }
            }

            #pragma unroll
            for (int j = 0; j < 8; ++j) {
                int k = t * KTILE + kg + 16 * j;
                float e2 = e2p[l * K_CB + k];
                #pragma unroll
                for (int i = 0; i < 8; ++i) {
                    float sc = fmaf(-2.0f, acc[i][j], e2);
                    if (sc < rbest[i])       { rbest2[i] = rbest[i]; rbest[i] = sc; ridx[i] = k; }
                    else if (sc < rbest2[i]) { rbest2[i] = sc; }
                }
            }
        }

        #pragma unroll
        for (int i = 0; i < 8; ++i) {
            float b = rbest[i], b2 = rbest2[i];
            int   ix = ridx[i];
            #pragma unroll
            for (int m = 1; m < 16; m <<= 1) {
                float bo  = __shfl_xor(b, m, 64);
                float b2o = __shfl_xor(b2, m, 64);
                int   io  = __shfl_xor(ix, m, 64);
                float nb2 = fminf(fmaxf(b, bo), fminf(b2, b2o));
                if (bo < b || (bo == b && io < ix)) { b = bo; ix = io; }
                b2 = nb2;
            }
            rbest[i] = b; rbest2[i] = b2; ridx[i] = ix;
            if (b2 - b <= MARGIN_F32) flagmask |= (1 << i);
        }
        if (kg == 0) {
            #pragma unroll
            for (int i = 0; i < 8; ++i) bidxs[l][rg + 16 * i] = ridx[i];
        }
        __syncthreads();

        {
            int r = tid >> 1, hh = tid & 1;
            int bi = bidxs[l][r];
            const float4* q = (const float4*)(cbl + (size_t)bi * D_DIM + hh * 64);
            #pragma unroll
            for (int c = 0; c < 16; ++c) {
                float4 v = q[c];
                float4* p = (float4*)&rrs[r * LSTR + hh * 64 + c * 4];
                float4 x = *p;
                x.x -= v.x; x.y -= v.y; x.z -= v.z; x.w -= v.w;
                *p = x;
            }
        }
        __syncthreads();
    }

    if (kg == 0 && flagmask) {
        #pragma unroll
        for (int i = 0; i < 8; ++i)
            if (flagmask & (1 << i)) {
                unsigned pos = atomicAdd(flagcnt, 1u);
                if (pos < flagcap) flaglist[pos] = row0 + rg + 16 * i;
            }
    }

    {
        int r = tid >> 1, hh = tid & 1;
        const float4* r0 = (const float4*)(residual + (size_t)(row0 + r) * D_DIM + hh * 64);
        float4* op = (float4*)(out + (size_t)(row0 + r) * D_DIM + hh * 64);
        #pragma unroll
        for (int c = 0; c < 16; ++c) {
            float4 a = r0[c];
            float4 b = *(const float4*)&rrs[r * LSTR + hh * 64 + c * 4];
            op[c] = make_float4(a.x - b.x, a.y - b.y, a.z - b.z, a.w - b.w);
        }
    }
    if (tid < BROWS) {
        float4* cp = (float4*)(out + (size_t)B * D_DIM + (size_t)(row0 + tid) * L_LVL);
        *cp = make_float4((float)bidxs[0][tid], (float)bidxs[1][tid],
                          (float)bidxs[2][tid], (float)bidxs[3][tid]);
    }
}

// ---------------- fixup: replicated reference semantics per flagged row ----------------
__global__ __launch_bounds__(256, 1)
void rvq_fixup(const float* __restrict__ residual,
               const float* __restrict__ codebooks,
               const float* __restrict__ e2p,
               const unsigned* __restrict__ flagcnt,
               const unsigned* __restrict__ flaglist,
               unsigned flagcap, float* __restrict__ out, int B) {
    __shared__ float rbuf[D_DIM];
    __shared__ float r0buf[D_DIM];
    __shared__ float x2s;
    __shared__ float redS[256];
    __shared__ int   redK[256];
    __shared__ int   codes_s[L_LVL];

    unsigned n = *flagcnt;
    if (n > flagcap) n = flagcap;

    for (unsigned b = blockIdx.x; b < n; b += gridDim.x) {
        int row = (int)flaglist[b];
        if (threadIdx.x < 32) {
            float4 v = ((const float4*)(residual + (size_t)row * D_DIM))[threadIdx.x];
            *(float4*)&rbuf[threadIdx.x * 4]  = v;
            *(float4*)&r0buf[threadIdx.x * 4] = v;
        }
        __syncthreads();

        for (int l = 0; l < L_LVL; ++l) {
            const float* cbl = codebooks + (size_t)l * K_CB * D_DIM;
            if (threadIdx.x == 0) {
                float r8[8];
                #pragma unroll
                for (int j = 0; j < 8; ++j) r8[j] = mulr(rbuf[j], rbuf[j]);
                for (int bb = 1; bb < 16; ++bb)
                    #pragma unroll
                    for (int j = 0; j < 8; ++j) r8[j] += mulr(rbuf[bb * 8 + j], rbuf[bb * 8 + j]);
                x2s = ((r8[0] + r8[1]) + (r8[2] + r8[3])) + ((r8[4] + r8[5]) + (r8[6] + r8[7]));
            }
            __syncthreads();
            float x2 = x2s;

            float bS = 3.4e38f;
            int   bK = 0x7fffffff;
            for (int m = 0; m < 4; ++m) {
                int k = threadIdx.x + m * 256;
                const float4* ek = (const float4*)(cbl + (size_t)k * D_DIM);
                double dd = 0.0;
                for (int c = 0; c < 32; ++c) {
                    float4 v = ek[c];
                    dd = fma((double)v.x, (double)rbuf[c * 4 + 0], dd);
                    dd = fma((double)v.y, (double)rbuf[c * 4 + 1], dd);
                    dd = fma((double)v.z, (double)rbuf[c * 4 + 2], dd);
                    dd = fma((double)v.w, (double)rbuf[c * 4 + 3], dd);
                }
                float M = (float)dd;
                float A = x2 + e2p[l * K_CB + k];
                float S = A - 2.0f * M;
                if (S < bS || (S == bS && k < bK)) { bS = S; bK = k; }
            }
            redS[threadIdx.x] = bS; redK[threadIdx.x] = bK;
            __syncthreads();
            for (int s = 128; s > 0; s >>= 1) {
                if (threadIdx.x < (unsigned)s) {
                    float So = redS[threadIdx.x + s];
                    int   Ko = redK[threadIdx.x + s];
                    if (So < redS[threadIdx.x] ||
                        (So == redS[threadIdx.x] && Ko < redK[threadIdx.x])) {
                        redS[threadIdx.x] = So; redK[threadIdx.x] = Ko;
                    }
                }
                __syncthreads();
            }
            int bi = redK[0];
            if (threadIdx.x == 0) codes_s[l] = bi;
            if (threadIdx.x < 32) {
                float4 q = ((const float4*)(cbl + (size_t)bi * D_DIM))[threadIdx.x];
                float4* p = (float4*)&rbuf[threadIdx.x * 4];
                float4 x = *p;
                x.x -= q.x; x.y -= q.y; x.z -= q.z; x.w -= q.w;
                *p = x;
            }
            __syncthreads();
        }

        if (threadIdx.x < 32) {
            float4 a = *(float4*)&r0buf[threadIdx.x * 4];
            float4 r = *(float4*)&rbuf[threadIdx.x * 4];
            ((float4*)(out + (size_t)row * D_DIM))[threadIdx.x] =
                make_float4(a.x - r.x, a.y - r.y, a.z - r.z, a.w - r.w);
        }
        if (threadIdx.x == 0) {
            float4* cp = (float4*)(out + (size_t)B * D_DIM + (size_t)row * L_LVL);
            *cp = make_float4((float)codes_s[0], (float)codes_s[1],
                              (float)codes_s[2], (float)codes_s[3]);
        }
        __syncthreads();
    }
}

extern "C" void kernel_launch(void* const* d_in, const int* in_sizes, int n_in,
                              void* d_out, int out_size, void* d_ws, size_t ws_size,
                              hipStream_t stream) {
    const float* residual  = (const float*)d_in[0];
    const float* codebooks = (const float*)d_in[1];
    float* out = (float*)d_out;
    int B = in_sizes[0] / D_DIM;  // 131072

    const size_t E2_BYTES = LK * sizeof(float);          // 16 KB
    const size_t CB_BYTES = (size_t)LKD * 2;             // 1 MB each
    const size_t mfma_need = E2_BYTES + 2 * CB_BYTES + 64 + 65536;

    if (ws_size >= mfma_need) {
        float*    e2p      = (float*)d_ws;
        __bf16*   cbh      = (__bf16*)((char*)d_ws + E2_BYTES);
        __bf16*   cblo     = (__bf16*)((char*)d_ws + E2_BYTES + CB_BYTES);
        unsigned* flagcnt  = (unsigned*)((char*)d_ws + E2_BYTES + 2 * CB_BYTES);
        unsigned* flaglist = flagcnt + 16;
        unsigned  flagcap  = (unsigned)((ws_size - (E2_BYTES + 2 * CB_BYTES + 64)) / 4);
        if (flagcap > (unsigned)B) flagcap = (unsigned)B;

        hipMemsetAsync(flagcnt, 0, sizeof(unsigned), stream);
        hipLaunchKernelGGL(rvq_e2, dim3(16), dim3(256), 0, stream, codebooks, e2p);
        hipLaunchKernelGGL(rvq_split, dim3(LKD / 4 / 256), dim3(256), 0, stream,
                           codebooks, cbh, cblo);
        hipLaunchKernelGGL(rvq_mfma, dim3(B / 128), dim3(256), 0, stream,
                           residual, codebooks, cbh, cblo, e2p,
                           flagcnt, flaglist, flagcap, out, B);
        hipLaunchKernelGGL(rvq_fixup, dim3(512), dim3(256), 0, stream,
                           residual, codebooks, e2p, flagcnt, flaglist, flagcap, out, B);
    } else {
        float*    e2p      = (float*)d_ws;
        unsigned* flagcnt  = (unsigned*)((char*)d_ws + E2_BYTES);
        unsigned* flaglist = flagcnt + 16;
        unsigned  flagcap  = 0;
        if (ws_size > E2_BYTES + 64)
            flagcap = (unsigned)((ws_size - E2_BYTES - 64) / sizeof(unsigned));
        if (flagcap > (unsigned)B) flagcap = (unsigned)B;

        hipMemsetAsync(flagcnt, 0, sizeof(unsigned), stream);
        hipLaunchKernelGGL(rvq_e2, dim3(16), dim3(256), 0, stream, codebooks, e2p);
        hipLaunchKernelGGL(rvq_main, dim3(B / BROWS), dim3(256), 0, stream,
                           residual, codebooks, e2p, flagcnt, flaglist, flagcap, out, B);
        hipLaunchKernelGGL(rvq_fixup, dim3(512), dim3(256), 0, stream,
                           residual, codebooks, e2p, flagcnt, flaglist, flagcap, out, B);
    }
}

// Round 8
// 877.608 us; speedup vs baseline: 19.8918x; 1.0658x over previous
//
#include <hip/hip_runtime.h>
#include <math.h>

// Residual VQ matching a float32 numpy reference (R3/R6/R7-verified semantics):
//   scores = x2 + e2 - 2*(res @ emb.T) in f32, argmin = first-min.
// R8: bf16x3 MFMA hot path with counted-vmcnt software pipeline (T3/T4):
//   distance-2 prefetch via global_load_lds, raw s_barrier + s_waitcnt vmcnt(4)
//   (never drain mid-loop), sched_barrier fences. e2 per-level in LDS (4KB),
//   3 blocks/CU. Margin-flagged rows -> exact replicated-f32 fixup kernel.

#define D_DIM 128
#define K_CB  1024
#define L_LVL 4
#define LK    (L_LVL * K_CB)
#define LKD   (LK * D_DIM)
#define NT    32
#define MARGIN_MFMA 1e-3f

typedef __bf16 bf16x8 __attribute__((ext_vector_type(8)));
typedef float  f32x16 __attribute__((ext_vector_type(16)));

// force f32 rounding of a product (blocks fma contraction)
static __device__ __forceinline__ float mulr(float a, float b) {
    float p = a * b; asm volatile("" : "+v"(p)); return p;
}

// ---------------- prep: bf16 hi/lo split + pairwise e2 + flag zero ----------------
__global__ void rvq_prep(const float* __restrict__ cb,
                         __bf16* __restrict__ hi, __bf16* __restrict__ lo,
                         float* __restrict__ e2p, unsigned* __restrict__ flagcnt) {
    int i = blockIdx.x * blockDim.x + threadIdx.x;   // over LKD/4
    if (i == 0) *flagcnt = 0;
    float4 v = ((const float4*)cb)[i];
    float f[4] = {v.x, v.y, v.z, v.w};
    #pragma unroll
    for (int e = 0; e < 4; ++e) {
        __bf16 h = (__bf16)f[e];
        hi[i * 4 + e] = h;
        lo[i * 4 + e] = (__bf16)(f[e] - (float)h);
    }
    if ((i & 31) == 0) {     // one lane per codeword row: numpy-pairwise ||e||^2
        int row = i >> 5;
        const float* ep = cb + (size_t)row * D_DIM;
        float r8[8];
        #pragma unroll
        for (int j = 0; j < 8; ++j) r8[j] = mulr(ep[j], ep[j]);
        #pragma unroll
        for (int b = 1; b < 16; ++b)
            #pragma unroll
            for (int j = 0; j < 8; ++j) r8[j] += mulr(ep[b * 8 + j], ep[b * 8 + j]);
        e2p[row] = ((r8[0] + r8[1]) + (r8[2] + r8[3])) + ((r8[4] + r8[5]) + (r8[6] + r8[7]));
    }
}

// ---------------- stage one 32-codeword tile (hi+lo) into LDS ----------------
static __device__ __forceinline__ void stage_tile(
    const __bf16* cbhL, const __bf16* cblL, int t,
    __bf16* dsth, __bf16* dstl, int wave, int lane) {
    const int k0 = t * 32;
    const size_t off = (size_t)(k0 + (lane & 31)) * D_DIM + (lane >> 5) * 8;
    #pragma unroll
    for (int c = 0; c < 2; ++c) {
        const int it = wave * 2 + c;
        __builtin_amdgcn_global_load_lds(
            (const __attribute__((address_space(1))) void*)(cbhL + off + it * 16),
            (__attribute__((address_space(3))) void*)(dsth + it * 512), 16, 0, 0);
        __builtin_amdgcn_global_load_lds(
            (const __attribute__((address_space(1))) void*)(cblL + off + it * 16),
            (__attribute__((address_space(3))) void*)(dstl + it * 512), 16, 0, 0);
    }
}

// ---------------- MFMA hot kernel ----------------
__global__ __launch_bounds__(256, 3)
void rvq_mfma(const float* __restrict__ residual,
              const float* __restrict__ codebooks,
              const __bf16* __restrict__ cbh, const __bf16* __restrict__ cbl,
              const float* __restrict__ e2p,
              unsigned* __restrict__ flagcnt, unsigned* __restrict__ flaglist,
              unsigned flagcap, float* __restrict__ out, int B) {
    __shared__ __align__(16) __bf16 bufh[2][32 * D_DIM];   // 16 KB
    __shared__ __align__(16) __bf16 bufl[2][32 * D_DIM];   // 16 KB
    __shared__ float e2s[K_CB];                            // 4 KB (current level)
    __shared__ int   bidxs[L_LVL][128];
    __shared__ unsigned char flg[128];

    const int tid  = threadIdx.x;
    const int wave = tid >> 6;
    const int lane = tid & 63;
    const int col  = lane & 31;
    const int h    = lane >> 5;
    const int rb   = wave * 32;
    const int grow = blockIdx.x * 128 + rb + col;

    if (tid < 128) flg[tid] = 0;

    // A fragments: residual row split to bf16 hi/lo, in registers.
    // lane covers row=rb+col, D-elems kk*16 + h*8 + e (same mapping as staged B).
    bf16x8 Ah[8], Al[8];
    {
        const float* rowp = residual + (size_t)grow * D_DIM;
        #pragma unroll
        for (int kk = 0; kk < 8; ++kk) {
            const int d0 = kk * 16 + h * 8;
            float4 a = *(const float4*)(rowp + d0);
            float4 b = *(const float4*)(rowp + d0 + 4);
            float f[8] = {a.x, a.y, a.z, a.w, b.x, b.y, b.z, b.w};
            #pragma unroll
            for (int e = 0; e < 8; ++e) {
                __bf16 hh = (__bf16)f[e];
                Ah[kk][e] = hh;
                Al[kk][e] = (__bf16)(f[e] - (float)hh);
            }
        }
    }

    for (int l = 0; l < L_LVL; ++l) {
        const __bf16* cbhL = cbh + (size_t)l * K_CB * D_DIM;
        const __bf16* cblL = cbl + (size_t)l * K_CB * D_DIM;

        // drain any stray vmem (residual/A-build or last level's gathers) so the
        // counted-vmcnt pipeline below sees only its own staging loads.
        asm volatile("s_waitcnt vmcnt(0)" ::: "memory");

        // current level's e2 -> LDS (visible to all waves after t=0 top barrier)
        ((float4*)e2s)[tid] = ((const float4*)(e2p + l * K_CB))[tid];

        float rbest[16], rbest2[16]; int ridx[16];
        #pragma unroll
        for (int s = 0; s < 16; ++s) { rbest[s] = 3.4e38f; rbest2[s] = 3.4e38f; ridx[s] = 0x7fffffff; }

        // distance-2 prologue: 8 loads in flight per wave
        stage_tile(cbhL, cblL, 0, &bufh[0][0], &bufl[0][0], wave, lane);
        stage_tile(cbhL, cblL, 1, &bufh[1][0], &bufl[1][0], wave, lane);

        for (int t = 0; t < NT; ++t) {
            const int cur = t & 1;
            // own tile-t loads are all but the newest 4 (tile t+1's) -> counted wait
            if (t < NT - 1) asm volatile("s_waitcnt vmcnt(4) lgkmcnt(0)" ::: "memory");
            else            asm volatile("s_waitcnt vmcnt(0) lgkmcnt(0)" ::: "memory");
            __builtin_amdgcn_s_barrier();          // all waves' quarters of t landed
            __builtin_amdgcn_sched_barrier(0);

            const float e2k = e2s[t * 32 + col];   // issued early, used after MFMAs

            f32x16 accA, accB;
            #pragma unroll
            for (int s = 0; s < 16; ++s) { accA[s] = 0.f; accB[s] = 0.f; }

            const __bf16* bh = &bufh[cur][0];
            const __bf16* bl = &bufl[cur][0];
            #pragma unroll
            for (int kk = 0; kk < 8; ++kk) {
                bf16x8 Bh = *(const bf16x8*)(bh + kk * 512 + lane * 8);
                bf16x8 Bl = *(const bf16x8*)(bl + kk * 512 + lane * 8);
                if (kk & 1) {
                    accB = __builtin_amdgcn_mfma_f32_32x32x16_bf16(Ah[kk], Bh, accB, 0, 0, 0);
                    accB = __builtin_amdgcn_mfma_f32_32x32x16_bf16(Ah[kk], Bl, accB, 0, 0, 0);
                    accB = __builtin_amdgcn_mfma_f32_32x32x16_bf16(Al[kk], Bh, accB, 0, 0, 0);
                } else {
                    accA = __builtin_amdgcn_mfma_f32_32x32x16_bf16(Ah[kk], Bh, accA, 0, 0, 0);
                    accA = __builtin_amdgcn_mfma_f32_32x32x16_bf16(Ah[kk], Bl, accA, 0, 0, 0);
                    accA = __builtin_amdgcn_mfma_f32_32x32x16_bf16(Al[kk], Bh, accA, 0, 0, 0);
                }
            }

            __builtin_amdgcn_sched_barrier(0);
            __builtin_amdgcn_s_barrier();          // all waves done reading buf[cur]
            asm volatile("" ::: "memory");
            if (t + 2 < NT)                        // overwrite just-freed buffer
                stage_tile(cbhL, cblL, t + 2, &bufh[cur][0], &bufl[cur][0], wave, lane);

            // scoring (registers + stable e2s) overlaps the in-flight staging
            const int k = t * 32 + col;
            #pragma unroll
            for (int s = 0; s < 16; ++s) {
                float sc = fmaf(-2.f, accA[s] + accB[s], e2k);
                if (sc < rbest[s])       { rbest2[s] = rbest[s]; rbest[s] = sc; ridx[s] = k; }
                else if (sc < rbest2[s]) { rbest2[s] = sc; }
            }
        }

        // merge top-2 across the 32 cols (within each 32-lane half), first-min
        #pragma unroll
        for (int s = 0; s < 16; ++s) {
            float b = rbest[s], b2 = rbest2[s]; int ix = ridx[s];
            #pragma unroll
            for (int m = 1; m <= 16; m <<= 1) {
                float bo  = __shfl_xor(b,  m, 64);
                float b2o = __shfl_xor(b2, m, 64);
                int   io  = __shfl_xor(ix, m, 64);
                float nb2 = fminf(fmaxf(b, bo), fminf(b2, b2o));
                if (bo < b || (bo == b && io < ix)) { b = bo; ix = io; }
                b2 = nb2;
            }
            const int rloc = (s & 3) + 8 * (s >> 2) + 4 * h;   // verified C row map
            if (col == 0) {
                bidxs[l][rb + rloc] = ix;
                if (b2 - b <= MARGIN_MFMA) flg[rb + rloc] = 1;
            }
        }
        __syncthreads();

        // residual update in f32, re-split to bf16 pair (drift << margin budget)
        {
            const int bi = bidxs[l][rb + col];
            const float* qp = codebooks + ((size_t)l * K_CB + bi) * D_DIM;
            #pragma unroll
            for (int kk = 0; kk < 8; ++kk) {
                const int d0 = kk * 16 + h * 8;
                float4 qa = *(const float4*)(qp + d0);
                float4 qb = *(const float4*)(qp + d0 + 4);
                float q[8] = {qa.x, qa.y, qa.z, qa.w, qb.x, qb.y, qb.z, qb.w};
                #pragma unroll
                for (int e = 0; e < 8; ++e) {
                    float r = ((float)Ah[kk][e] + (float)Al[kk][e]) - q[e];
                    __bf16 hh = (__bf16)r;
                    Ah[kk][e] = hh;
                    Al[kk][e] = (__bf16)(r - (float)hh);
                }
            }
        }
    }

    // quantized = r0 - r_final
    {
        const float* rowp = residual + (size_t)grow * D_DIM;
        float* op = out + (size_t)grow * D_DIM;
        #pragma unroll
        for (int kk = 0; kk < 8; ++kk) {
            const int d0 = kk * 16 + h * 8;
            float4 a = *(const float4*)(rowp + d0);
            float4 b = *(const float4*)(rowp + d0 + 4);
            float f[8] = {a.x, a.y, a.z, a.w, b.x, b.y, b.z, b.w};
            float o[8];
            #pragma unroll
            for (int e = 0; e < 8; ++e)
                o[e] = f[e] - ((float)Ah[kk][e] + (float)Al[kk][e]);
            *(float4*)(op + d0)     = make_float4(o[0], o[1], o[2], o[3]);
            *(float4*)(op + d0 + 4) = make_float4(o[4], o[5], o[6], o[7]);
        }
    }
    if (tid < 128) {
        int row = blockIdx.x * 128 + tid;
        float4* cp = (float4*)(out + (size_t)B * D_DIM + (size_t)row * L_LVL);
        *cp = make_float4((float)bidxs[0][tid], (float)bidxs[1][tid],
                          (float)bidxs[2][tid], (float)bidxs[3][tid]);
        if (flg[tid]) {
            unsigned pos = atomicAdd(flagcnt, 1u);
            if (pos < flagcap) flaglist[pos] = row;
        }
    }
}

// ---------------- fixup: replicated reference semantics per flagged row ----------------
__global__ __launch_bounds__(256, 1)
void rvq_fixup(const float* __restrict__ residual,
               const float* __restrict__ codebooks,
               const float* __restrict__ e2p,
               const unsigned* __restrict__ flagcnt,
               const unsigned* __restrict__ flaglist,
               unsigned flagcap, float* __restrict__ out, int B) {
    __shared__ float rbuf[D_DIM];
    __shared__ float r0buf[D_DIM];
    __shared__ float x2s;
    __shared__ float redS[256];
    __shared__ int   redK[256];
    __shared__ int   codes_s[L_LVL];

    unsigned n = *flagcnt;
    if (n > flagcap) n = flagcap;

    for (unsigned b = blockIdx.x; b < n; b += gridDim.x) {
        int row = (int)flaglist[b];
        if (threadIdx.x < 32) {
            float4 v = ((const float4*)(residual + (size_t)row * D_DIM))[threadIdx.x];
            *(float4*)&rbuf[threadIdx.x * 4]  = v;
            *(float4*)&r0buf[threadIdx.x * 4] = v;
        }
        __syncthreads();

        for (int l = 0; l < L_LVL; ++l) {
            const float* cbl = codebooks + (size_t)l * K_CB * D_DIM;
            if (threadIdx.x == 0) {
                float r8[8];
                #pragma unroll
                for (int j = 0; j < 8; ++j) r8[j] = mulr(rbuf[j], rbuf[j]);
                for (int bb = 1; bb < 16; ++bb)
                    #pragma unroll
                    for (int j = 0; j < 8; ++j) r8[j] += mulr(rbuf[bb * 8 + j], rbuf[bb * 8 + j]);
                x2s = ((r8[0] + r8[1]) + (r8[2] + r8[3])) + ((r8[4] + r8[5]) + (r8[6] + r8[7]));
            }
            __syncthreads();
            float x2 = x2s;

            float bS = 3.4e38f;
            int   bK = 0x7fffffff;
            for (int m = 0; m < 4; ++m) {
                int k = threadIdx.x + m * 256;
                const float4* ek = (const float4*)(cbl + (size_t)k * D_DIM);
                double dd = 0.0;
                for (int c = 0; c < 32; ++c) {
                    float4 v = ek[c];
                    dd = fma((double)v.x, (double)rbuf[c * 4 + 0], dd);
                    dd = fma((double)v.y, (double)rbuf[c * 4 + 1], dd);
                    dd = fma((double)v.z, (double)rbuf[c * 4 + 2], dd);
                    dd = fma((double)v.w, (double)rbuf[c * 4 + 3], dd);
                }
                float M = (float)dd;                 // fl32(exact dot)
                float A = x2 + e2p[l * K_CB + k];    // fl32(x2 + e2)
                float S = A - 2.0f * M;              // final f32 rounding
                if (S < bS || (S == bS && k < bK)) { bS = S; bK = k; }
            }
            redS[threadIdx.x] = bS; redK[threadIdx.x] = bK;
            __syncthreads();
            for (int s = 128; s > 0; s >>= 1) {
                if (threadIdx.x < (unsigned)s) {
                    float So = redS[threadIdx.x + s];
                    int   Ko = redK[threadIdx.x + s];
                    if (So < redS[threadIdx.x] ||
                        (So == redS[threadIdx.x] && Ko < redK[threadIdx.x])) {
                        redS[threadIdx.x] = So; redK[threadIdx.x] = Ko;
                    }
                }
                __syncthreads();
            }
            int bi = redK[0];
            if (threadIdx.x == 0) codes_s[l] = bi;
            if (threadIdx.x < 32) {
                float4 q = ((const float4*)(cbl + (size_t)bi * D_DIM))[threadIdx.x];
                float4* p = (float4*)&rbuf[threadIdx.x * 4];
                float4 x = *p;
                x.x -= q.x; x.y -= q.y; x.z -= q.z; x.w -= q.w;
                *p = x;
            }
            __syncthreads();
        }

        if (threadIdx.x < 32) {
            float4 a = *(float4*)&r0buf[threadIdx.x * 4];
            float4 r = *(float4*)&rbuf[threadIdx.x * 4];
            ((float4*)(out + (size_t)row * D_DIM))[threadIdx.x] =
                make_float4(a.x - r.x, a.y - r.y, a.z - r.z, a.w - r.w);
        }
        if (threadIdx.x == 0) {
            float4* cp = (float4*)(out + (size_t)B * D_DIM + (size_t)row * L_LVL);
            *cp = make_float4((float)codes_s[0], (float)codes_s[1],
                              (float)codes_s[2], (float)codes_s[3]);
        }
        __syncthreads();
    }
}

extern "C" void kernel_launch(void* const* d_in, const int* in_sizes, int n_in,
                              void* d_out, int out_size, void* d_ws, size_t ws_size,
                              hipStream_t stream) {
    const float* residual  = (const float*)d_in[0];
    const float* codebooks = (const float*)d_in[1];
    float* out = (float*)d_out;
    int B = in_sizes[0] / D_DIM;  // 131072

    const size_t E2_BYTES = LK * sizeof(float);          // 16 KB
    const size_t CB_BYTES = (size_t)LKD * 2;             // 1 MB each (hi, lo)

    float*    e2p      = (float*)d_ws;
    __bf16*   cbh      = (__bf16*)((char*)d_ws + E2_BYTES);
    __bf16*   cblo     = (__bf16*)((char*)d_ws + E2_BYTES + CB_BYTES);
    unsigned* flagcnt  = (unsigned*)((char*)d_ws + E2_BYTES + 2 * CB_BYTES);
    unsigned* flaglist = flagcnt + 16;
    unsigned  flagcap  = (unsigned)((ws_size - (E2_BYTES + 2 * CB_BYTES + 64)) / 4);
    if (flagcap > (unsigned)B) flagcap = (unsigned)B;

    hipLaunchKernelGGL(rvq_prep, dim3(LKD / 4 / 256), dim3(256), 0, stream,
                       codebooks, cbh, cblo, e2p, flagcnt);
    hipLaunchKernelGGL(rvq_mfma, dim3(B / 128), dim3(256), 0, stream,
                       residual, codebooks, cbh, cblo, e2p,
                       flagcnt, flaglist, flagcap, out, B);
    hipLaunchKernelGGL(rvq_fixup, dim3(512), dim3(256), 0, stream,
                       residual, codebooks, e2p, flagcnt, flaglist, flagcap, out, B);
}